// Round 13
// baseline (38.548 us; speedup 1.0000x reference)
//
#include <hip/hip_runtime.h>

#define BB 4
#define CC 512    // C_CTX
#define TDIM 512  // T
#define HH 128

// ---------------- prep: key/query/value projections (f32 to ws) -------------
__global__ __launch_bounds__(128) void prep_kernel(
    const float* __restrict__ ctx_x, const float* __restrict__ ctx_y,
    const float* __restrict__ tgt_x,
    const float* __restrict__ W_in, const float* __restrict__ b_in,
    const float* __restrict__ W_ctx, const float* __restrict__ b_ctx,
    float* __restrict__ key, float* __restrict__ query, float* __restrict__ value)
{
    int row = blockIdx.x;     // b*512 + r
    int h   = threadIdx.x;    // 0..127

    float4 cx = ((const float4*)ctx_x)[row];
    float2 cy = ((const float2*)ctx_y)[row];
    float4 tx = ((const float4*)tgt_x)[row];

    float wi0 = W_in[0*HH+h], wi1 = W_in[1*HH+h], wi2 = W_in[2*HH+h];
    float wi3 = W_in[3*HH+h], wi4 = W_in[4*HH+h];
    float wc0 = W_ctx[0*HH+h], wc1 = W_ctx[1*HH+h], wc2 = W_ctx[2*HH+h];
    float bi  = b_in[h], bc = b_ctx[h];

    value[row*HH+h] = fmaf(cx.x,wi0, fmaf(cx.y,wi1, fmaf(cx.z,wi2, fmaf(cy.x,wi3, fmaf(cy.y,wi4, bi)))));
    key  [row*HH+h] = fmaf(cx.x,wc0, fmaf(cx.y,wc1, fmaf(cx.z,wc2, bc)));
    query[row*HH+h] = fmaf(tx.x,wc0, fmaf(tx.y,wc1, fmaf(tx.z,wc2, bc)));
}

// ---------- score+softmax+PV: 1024 blocks (b x t-quad x c-half), 4 waves.
// Wave = (t-quad, 64 c-rows), fully independent until one final merge barrier.
// Writes unnormalized weighted partial (4x128) + (M,L) per t to ws.
__global__ __launch_bounds__(256) void score_pv_kernel(
    const float* __restrict__ key, const float* __restrict__ query,
    const float* __restrict__ value,
    float* __restrict__ bp, float2* __restrict__ bml)
{
    const int bx    = blockIdx.x;          // (b*128 + tq)*2 + chalf
    const int chalf = bx & 1;
    const int tq    = (bx >> 1) & 127;
    const int b     = bx >> 8;
    const int t0    = tq * 4;
    const int c0    = chalf * 256;
    const int tid   = threadIdx.x;
    const int w     = tid >> 6;            // wave 0..3 -> c [c0+w*64, +64)
    const int lane  = tid & 63;

    __shared__ __align__(16) float s_w[4][4][64];     // 4 KB wave-private scores
    __shared__ __align__(16) float pT_w[4][64][4];    // 4 KB wave-private exp^T
    __shared__ __align__(16) float2 wml[4][4];        // (m,l) per wave per t
    __shared__ __align__(16) float partial[4][4][HH]; // 8 KB wave PV partials

    // --- score role: (cl = c-quad 0..7, hq = h-oct 0..7); q in 64 VGPR ---
    const int cl = lane >> 3;
    const int hq = lane & 7;
    float4 qr[4][4];
    #pragma unroll
    for (int t = 0; t < 4; ++t)
        #pragma unroll
        for (int j = 0; j < 4; ++j)
            qr[t][j] = *(const float4*)&query[(b*TDIM + t0 + t)*HH + j*32 + hq*4];

    const int cw0 = c0 + w*64;

    // ---- SCORE: 2 passes x 32 rows ----
    #pragma unroll 1
    for (int pass = 0; pass < 2; ++pass) {
        const float* kp = &key[(b*CC + cw0 + pass*32 + cl*4)*HH];
        float a0[4], a1[4], a2[4], a3[4];
        #pragma unroll
        for (int t = 0; t < 4; ++t) { a0[t]=0.f; a1[t]=0.f; a2[t]=0.f; a3[t]=0.f; }
        #pragma unroll
        for (int j = 0; j < 4; ++j) {
            const int hb = j*32 + hq*4;
            float4 k0 = *(const float4*)(kp + 0*HH + hb);
            float4 k1 = *(const float4*)(kp + 1*HH + hb);
            float4 k2 = *(const float4*)(kp + 2*HH + hb);
            float4 k3 = *(const float4*)(kp + 3*HH + hb);
            #pragma unroll
            for (int t = 0; t < 4; ++t) {
                float4 qv = qr[t][j];
                a0[t] += fabsf(k0.x-qv.x)+fabsf(k0.y-qv.y)+fabsf(k0.z-qv.z)+fabsf(k0.w-qv.w);
                a1[t] += fabsf(k1.x-qv.x)+fabsf(k1.y-qv.y)+fabsf(k1.z-qv.z)+fabsf(k1.w-qv.w);
                a2[t] += fabsf(k2.x-qv.x)+fabsf(k2.y-qv.y)+fabsf(k2.z-qv.z)+fabsf(k2.w-qv.w);
                a3[t] += fabsf(k3.x-qv.x)+fabsf(k3.y-qv.y)+fabsf(k3.z-qv.z)+fabsf(k3.w-qv.w);
            }
        }
        #pragma unroll
        for (int t = 0; t < 4; ++t) {
            float v0=a0[t], v1=a1[t], v2=a2[t], v3=a3[t];
            v0 += __shfl_xor(v0,1); v0 += __shfl_xor(v0,2); v0 += __shfl_xor(v0,4);
            v1 += __shfl_xor(v1,1); v1 += __shfl_xor(v1,2); v1 += __shfl_xor(v1,4);
            v2 += __shfl_xor(v2,1); v2 += __shfl_xor(v2,2); v2 += __shfl_xor(v2,4);
            v3 += __shfl_xor(v3,1); v3 += __shfl_xor(v3,2); v3 += __shfl_xor(v3,4);
            if (hq == 0)
                *(float4*)&s_w[w][t][pass*32 + cl*4] =
                    make_float4(-0.5f*v0, -0.5f*v1, -0.5f*v2, -0.5f*v3);
        }
    }
    // same-wave LDS handoff: no barrier

    // ---- single-pass softmax (16-lane group tg owns t-row tg, 64 c) ----
    {
        const int tg = lane >> 4, ci = lane & 15;
        float4 x = *(const float4*)&s_w[w][tg][ci*4];
        float m = fmaxf(fmaxf(x.x, x.y), fmaxf(x.z, x.w));
        m = fmaxf(m, __shfl_xor(m,1)); m = fmaxf(m, __shfl_xor(m,2));
        m = fmaxf(m, __shfl_xor(m,4)); m = fmaxf(m, __shfl_xor(m,8));
        float e0 = __expf(x.x-m), e1 = __expf(x.y-m);
        float e2 = __expf(x.z-m), e3 = __expf(x.w-m);
        float sm = (e0+e1) + (e2+e3);
        sm += __shfl_xor(sm,1); sm += __shfl_xor(sm,2);
        sm += __shfl_xor(sm,4); sm += __shfl_xor(sm,8);
        pT_w[w][ci*4+0][tg] = e0;
        pT_w[w][ci*4+1][tg] = e1;
        pT_w[w][ci*4+2][tg] = e2;
        pT_w[w][ci*4+3][tg] = e3;
        if (ci == 0) wml[w][tg] = make_float2(m, sm);
    }
    // same-wave LDS handoff: no barrier

    // ---- PV over own 64 rows (reg acc) ----
    {
        const int cs = lane >> 5, hv = lane & 31;
        float4 acc[4];
        #pragma unroll
        for (int t = 0; t < 4; ++t) acc[t] = make_float4(0.f,0.f,0.f,0.f);
        const float* vp = &value[(b*CC + cw0 + cs*32)*HH + hv*4];
        #pragma unroll 8
        for (int i = 0; i < 32; ++i) {
            float4 p4 = *(const float4*)&pT_w[w][cs*32 + i][0];  // 2-addr broadcast
            float4 vv = *(const float4*)(vp + i*HH);             // coalesced
            acc[0].x=fmaf(p4.x,vv.x,acc[0].x); acc[0].y=fmaf(p4.x,vv.y,acc[0].y);
            acc[0].z=fmaf(p4.x,vv.z,acc[0].z); acc[0].w=fmaf(p4.x,vv.w,acc[0].w);
            acc[1].x=fmaf(p4.y,vv.x,acc[1].x); acc[1].y=fmaf(p4.y,vv.y,acc[1].y);
            acc[1].z=fmaf(p4.y,vv.z,acc[1].z); acc[1].w=fmaf(p4.y,vv.w,acc[1].w);
            acc[2].x=fmaf(p4.z,vv.x,acc[2].x); acc[2].y=fmaf(p4.z,vv.y,acc[2].y);
            acc[2].z=fmaf(p4.z,vv.z,acc[2].z); acc[2].w=fmaf(p4.z,vv.w,acc[2].w);
            acc[3].x=fmaf(p4.w,vv.x,acc[3].x); acc[3].y=fmaf(p4.w,vv.y,acc[3].y);
            acc[3].z=fmaf(p4.w,vv.z,acc[3].z); acc[3].w=fmaf(p4.w,vv.w,acc[3].w);
        }
        #pragma unroll
        for (int t = 0; t < 4; ++t) {
            acc[t].x += __shfl_xor(acc[t].x, 32);
            acc[t].y += __shfl_xor(acc[t].y, 32);
            acc[t].z += __shfl_xor(acc[t].z, 32);
            acc[t].w += __shfl_xor(acc[t].w, 32);
        }
        if (cs == 0) {
            #pragma unroll
            for (int t = 0; t < 4; ++t)
                *(float4*)&partial[w][t][hv*4] = acc[t];
        }
    }
    __syncthreads();

    // ---- flash-merge 4 waves -> unnormalized block partial + (M,L) ----
    #pragma unroll
    for (int e = tid; e < 4*HH; e += 256) {
        const int t = e >> 7, h = e & 127;
        float2 q0 = wml[0][t], q1 = wml[1][t], q2 = wml[2][t], q3 = wml[3][t];
        float M = fmaxf(fmaxf(q0.x,q1.x), fmaxf(q2.x,q3.x));
        float a0 = __expf(q0.x-M), a1 = __expf(q1.x-M);
        float a2 = __expf(q2.x-M), a3 = __expf(q3.x-M);
        float r = a0*partial[0][t][h] + a1*partial[1][t][h]
                + a2*partial[2][t][h] + a3*partial[3][t][h];
        bp[bx*512 + e] = r;
        if (h == 0) {
            float L = fmaf(a0,q0.y, fmaf(a1,q1.y, fmaf(a2,q2.y, a3*q3.y)));
            bml[bx*4 + t] = make_float2(M, L);
        }
    }
}

// ---------- merge c-halves + output projection: 512 blocks (b x t-quad) -----
__global__ __launch_bounds__(256) void proj_kernel(
    const float* __restrict__ bp, const float2* __restrict__ bml,
    const float* __restrict__ W_tgt, const float* __restrict__ b_tgt,
    float* __restrict__ out)
{
    const int bx  = blockIdx.x;            // b*128 + tq
    const int b   = bx >> 7;
    const int t0  = (bx & 127) * 4;
    const int tid = threadIdx.x;
    const int blk0 = bx*2, blk1 = bx*2 + 1;

    __shared__ __align__(16) float rep[4][HH];   // 2 KB

    #pragma unroll
    for (int e = tid; e < 4*HH; e += 256) {
        const int t = e >> 7;
        float2 m0 = bml[blk0*4 + t], m1 = bml[blk1*4 + t];
        float M  = fmaxf(m0.x, m1.x);
        float a0 = __expf(m0.x - M), a1 = __expf(m1.x - M);
        float invL = 1.f / fmaf(a0, m0.y, a1 * m1.y);
        (&rep[0][0])[e] = (a0*bp[blk0*512 + e] + a1*bp[blk1*512 + e]) * invL;
    }
    __syncthreads();

    {
        const int lt = tid >> 7, h = tid & 127;   // rows lt, lt+2
        float o0 = b_tgt[h], o1 = o0;
        for (int k = 0; k < HH; k += 4) {
            float4 r0 = *(const float4*)&rep[lt    ][k];
            float4 r1 = *(const float4*)&rep[lt + 2][k];
            float w0 = W_tgt[(k+0)*HH + h];
            float w1 = W_tgt[(k+1)*HH + h];
            float w2 = W_tgt[(k+2)*HH + h];
            float w3 = W_tgt[(k+3)*HH + h];
            o0 = fmaf(r0.x,w0, fmaf(r0.y,w1, fmaf(r0.z,w2, fmaf(r0.w,w3, o0))));
            o1 = fmaf(r1.x,w0, fmaf(r1.y,w1, fmaf(r1.z,w2, fmaf(r1.w,w3, o1))));
        }
        out[(b*TDIM + t0 + lt    )*HH + h] = o0;
        out[(b*TDIM + t0 + lt + 2)*HH + h] = o1;
    }
}

extern "C" void kernel_launch(void* const* d_in, const int* in_sizes, int n_in,
                              void* d_out, int out_size, void* d_ws, size_t ws_size,
                              hipStream_t stream) {
    const float* ctx_x = (const float*)d_in[0];
    const float* ctx_y = (const float*)d_in[1];
    const float* tgt_x = (const float*)d_in[2];
    const float* W_in  = (const float*)d_in[3];
    const float* b_in  = (const float*)d_in[4];
    const float* W_ctx = (const float*)d_in[5];
    const float* b_ctx = (const float*)d_in[6];
    const float* W_tgt = (const float*)d_in[7];
    const float* b_tgt = (const float*)d_in[8];

    float* ws    = (float*)d_ws;
    float* key   = ws;                      // 262144 f32
    float* query = ws + 1*BB*CC*HH;         // 262144
    float* value = ws + 2*BB*CC*HH;         // 262144
    float* bp    = ws + 3*BB*CC*HH;         // 1024 blocks * 512
    float2* bml  = (float2*)(bp + 1024*512);// 1024 blocks * 4

    prep_kernel<<<BB*CC, 128, 0, stream>>>(ctx_x, ctx_y, tgt_x,
                                           W_in, b_in, W_ctx, b_ctx,
                                           key, query, value);
    score_pv_kernel<<<BB*128*2, 256, 0, stream>>>(key, query, value, bp, bml);
    proj_kernel<<<BB*128, 256, 0, stream>>>(bp, bml, W_tgt, b_tgt, (float*)d_out);
}